// Round 7
// baseline (582.710 us; speedup 1.0000x reference)
//
#include <hip/hip_runtime.h>
#include <hip/hip_bf16.h>
#include <stdint.h>

// MaskedDeepDAN on MI355X (gfx950). B=8192, D_IN=2048, H=1024, C=1000.
// R7: restructured K-loop (AITER-style), attacking the two residual limits
// found in R6 (LDS read-back 2x amplification; vmcnt(0) barrier drain at
// only 8 waves/CU):
//  - tile 256x64xBK32, 512 threads (8 waves as 4m x 2n, wave region 64x32):
//    LDS reads/FLOP -25%; 512 blocks -> 2 blocks/CU = 16 waves/CU.
//  - 3 LDS buffers, depth-2 prefetch, fine-grained `s_waitcnt vmcnt(N)` +
//    raw `s_barrier` (never vmcnt(0) mid-loop): each wave waits only for its
//    own chunk-ci loads, leaving chunk-ci+1 in flight across the barrier.
//    Buffer-overwrite hazard safe: stage(ci+2) is issued post-barrier-ci and
//    targets buffer (ci-1)%3, whose reads were consumed (lgkm) pre-barrier.
// Carried (verified R3-R6): per-layer fused multi-source GEMM, fp32 bias+relu
// fold in regs, XCD-aware tile remap (FETCH 297->82MB), XOR LDS chunk swizzle
// (bank conflicts -> 0), size-signature input resolver + on-device dtype
// detection, vectorized prep.

typedef unsigned short ushort_t;
typedef __bf16 bf16x8 __attribute__((ext_vector_type(8)));
typedef float f32x4 __attribute__((ext_vector_type(4)));

__device__ __forceinline__ void gl_lds16(const void* g, void* l) {
  typedef __attribute__((address_space(1))) void gvoid;
  typedef __attribute__((address_space(3))) void lvoid;
  __builtin_amdgcn_global_load_lds((gvoid*)(void*)g, (lvoid*)l, 16, 0, 0);
}

__device__ __forceinline__ ushort_t f2b(float f) {
  __hip_bfloat16 h = (__hip_bfloat16)f;
  return *(ushort_t*)&h;
}

// ---------------- dtype detection (verified R3) ----------------
__global__ void detect_kernel(const ushort_t* x, const ushort_t* mf, int* flags) {
  __shared__ int s[4];
  if (threadIdx.x < 4) s[threadIdx.x] = 0;
  __syncthreads();
  int expout = 0, m3f80_even = 0, m3f80_odd = 0, mhi01 = 0;
  for (int k = threadIdx.x; k < 2048; k += 256) {
    ushort_t w = x[k];
    int e = (w >> 7) & 0xFF;
    if (e < 96 || e > 144) expout++;
    ushort_t mw = mf[k];
    if (mw == 0x3F80) { if (k & 1) m3f80_odd++; else m3f80_even++; }
    if ((mw >> 8) == 1) mhi01++;
  }
  atomicAdd(&s[0], expout);
  atomicAdd(&s[1], m3f80_even);
  atomicAdd(&s[2], m3f80_odd);
  atomicAdd(&s[3], mhi01);
  __syncthreads();
  if (threadIdx.x == 0) {
    flags[0] = (s[0] > 100) ? 1 : 0;
    int mmode = 0;
    if (s[1] > 100) mmode = 2;
    else if (s[2] > 100) mmode = 3;
    else if (s[3] > 200) mmode = 1;
    flags[1] = mmode;
  }
}

// -------- masking + dtype conversion (verified R4/R5) --------
struct PrepEnt {
  const void* w; size_t woff;
  const void* m; size_t moff;   // nullptr -> no mask
  ushort_t* o;
  int n;
  int valid;
};
struct PrepAll { PrepEnt e[25]; };

__global__ void prep_weights(PrepAll p, const int* flags) {
  const bool f32 = flags[0] != 0;
  const int mmode = flags[1];
  const PrepEnt e = p.e[blockIdx.y];
  const int nch = e.n >> 3;
  const int stride = blockDim.x * gridDim.x;
  for (int ci = blockIdx.x * blockDim.x + threadIdx.x; ci < nch; ci += stride) {
    const int i = ci << 3;
    ushort_t o[8] = {0, 0, 0, 0, 0, 0, 0, 0};
    if (i < e.valid) {
      ushort_t wb[8];
      if (f32) {
        const float* wp = (const float*)e.w + e.woff + i;
        float4 a = *(const float4*)wp;
        float4 b = *(const float4*)(wp + 4);
        wb[0] = f2b(a.x); wb[1] = f2b(a.y); wb[2] = f2b(a.z); wb[3] = f2b(a.w);
        wb[4] = f2b(b.x); wb[5] = f2b(b.y); wb[6] = f2b(b.z); wb[7] = f2b(b.w);
      } else {
        *(uint4*)wb = *(const uint4*)((const ushort_t*)e.w + e.woff + i);
      }
      unsigned mk = 0xFF;
      if (e.m) {
        mk = 0;
        if (mmode == 0) {
          const int4* mp = (const int4*)((const int*)e.m + e.moff + i);
          int4 a = mp[0], b = mp[1];
          mk = (a.x != 0) | ((a.y != 0) << 1) | ((a.z != 0) << 2) | ((a.w != 0) << 3) |
               ((b.x != 0) << 4) | ((b.y != 0) << 5) | ((b.z != 0) << 6) | ((b.w != 0) << 7);
        } else if (mmode == 1) {
          const uint2 mv = *(const uint2*)((const unsigned char*)e.m + e.moff + i);
          const unsigned char* mb = (const unsigned char*)&mv;
          for (int j = 0; j < 8; j++) mk |= (mb[j] != 0) << j;
        } else if (mmode == 2) {
          uint4 mv = *(const uint4*)((const ushort_t*)e.m + e.moff + i);
          const ushort_t* ms = (const ushort_t*)&mv;
          for (int j = 0; j < 8; j++) mk |= (ms[j] != 0) << j;
        } else {
          const uint4* mp = (const uint4*)((const unsigned int*)e.m + e.moff + i);
          uint4 a = mp[0], b = mp[1];
          const unsigned* u = (const unsigned*)&a;
          const unsigned* v = (const unsigned*)&b;
          for (int j = 0; j < 4; j++) mk |= (u[j] != 0) << j;
          for (int j = 0; j < 4; j++) mk |= (v[j] != 0) << (4 + j);
        }
      }
#pragma unroll
      for (int j = 0; j < 8; j++) o[j] = ((mk >> j) & 1) ? wb[j] : (ushort_t)0;
    }
    *(uint4*)(e.o + i) = *(uint4*)o;
  }
}

// ---------------- fused multi-source GEMM, 3-buffer pipelined ----------------
// C[M,N] = sum_s relu(A_s[M,K] * B_s[N,K]^T + bias_s)
// tile 256x64, BK=32; grid (8,64) = 512 blocks; block = 512 thr (8 waves).
struct GemmSrc { const ushort_t* A; const ushort_t* B; const ushort_t* bias; };
struct GemmArgs { GemmSrc s[4]; };

template <int NSRC, bool RELU, bool NGUARD>
__launch_bounds__(512, 4)
__global__ void gemm_multi(GemmArgs args, void* Cv, const int* of32flag,
                           int K, int N_real, int ldc)
{
  // 3 buffers: A 256x32 (8192 shorts), B 64x32 (2048 shorts) -> 60 KB total
  __shared__ __align__(16) ushort_t As[3][8192];
  __shared__ __align__(16) ushort_t Bs[3][2048];

  const bool of32 = (of32flag != nullptr) && (of32flag[0] != 0);
  __hip_bfloat16* C = (__hip_bfloat16*)Cv;
  float* Cf = (float*)Cv;

  const int tid  = threadIdx.x;
  const int lane = tid & 63;
  const int wave = tid >> 6;          // 0..7
  const int wm = (wave >> 1) * 64;    // 0,64,128,192
  const int wn = (wave & 1) * 32;     // 0,32
  const int fr = lane & 15;
  const int kg = lane >> 4;

  // XCD-aware remap (verified R6): all 16 N-tiles of one A-row-block group on
  // one XCD. lid%8 = XCD (round-robin); per XCD: 4 bm-tiles x 16 bn-tiles.
  const int lid = blockIdx.y * 8 + blockIdx.x;   // 0..511
  const int idx = lid >> 3;                      // 0..63
  const int bm  = ((lid & 7) * 4 + (idx >> 4)) * 256;
  const int bn  = (idx & 15) * 64;

  // staging map: thread t -> row t/4, XOR-swizzled k-chunk (verified R6)
  const int srow = tid >> 2;                           // 0..127
  const int scol = ((tid & 3) ^ ((srow >> 1) & 3)) * 8;
  const size_t aoff1 = (size_t)(bm + srow) * K + scol;
  const size_t aoff2 = aoff1 + (size_t)128 * K;        // rows +128
  const size_t boff  = (size_t)(bn + srow) * K + scol; // only waves 0-3 use
  const int ldsw = wave * 512;

  // per-wave loads per stage: waves 0-3 -> 3, waves 4-7 -> 2
  auto stage = [&](int buf, const GemmSrc& g, size_t ko) {
    gl_lds16(g.A + aoff1 + ko, &As[buf][ldsw]);
    gl_lds16(g.A + aoff2 + ko, &As[buf][4096 + ldsw]);
    if (wave < 4) gl_lds16(g.B + boff + ko, &Bs[buf][ldsw]);
  };

  // preload biases into registers (keeps global loads out of the K-loop so
  // the hand vmcnt bookkeeping stays exact)
  float bias_v[NSRC][2];
#pragma unroll
  for (int s = 0; s < NSRC; s++)
#pragma unroll
    for (int ni = 0; ni < 2; ni++)
      bias_v[s][ni] =
          (float)*(const __hip_bfloat16*)(args.s[s].bias + bn + wn + ni * 16 + fr);

  f32x4 acc[4][2], out_acc[4][2];
#pragma unroll
  for (int i = 0; i < 4; i++)
#pragma unroll
    for (int j = 0; j < 2; j++) {
      acc[i][j] = (f32x4){0.f, 0.f, 0.f, 0.f};
      out_acc[i][j] = (f32x4){0.f, 0.f, 0.f, 0.f};
    }

  const int kc  = K >> 5;        // chunks per source (>= 32)
  const int nch = NSRC * kc;

  // stage chunks 0 and 1
  int s_src = 0, s_k = 0;
  stage(0, args.s[0], 0);
  if (++s_k == kc) { s_k = 0; ++s_src; }
  stage(1, args.s[s_src < NSRC ? s_src : 0], (size_t)s_k * 32);
  if (++s_k == kc) { s_k = 0; ++s_src; }

  const int sw = kg ^ ((fr >> 1) & 3);   // fragment chunk swizzle (R6)

  int cb = 0, sb = 2;          // compute / stage buffer (mod 3)
  int c_src = 0, c_cnt = 0;    // compute-side source tracking

  for (int ci = 0; ci < nch; ++ci) {
    // wait until only chunk ci+1's loads remain in flight -> chunk ci staged
    if (ci + 1 < nch) {
      if (wave < 4) asm volatile("s_waitcnt vmcnt(3)" ::: "memory");
      else          asm volatile("s_waitcnt vmcnt(2)" ::: "memory");
    } else {
      asm volatile("s_waitcnt vmcnt(0)" ::: "memory");
    }
    asm volatile("s_barrier" ::: "memory");  // all waves' chunk-ci loads done

    // prefetch chunk ci+2 into buffer (ci+2)%3 = (ci-1)%3 (safe post-barrier)
    if (ci + 2 < nch) {
      stage(sb, args.s[s_src], (size_t)s_k * 32);
      if (++s_k == kc) { s_k = 0; ++s_src; }
      sb = (sb == 2) ? 0 : sb + 1;
    }

    const bf16x8* Asv = (const bf16x8*)As[cb];
    const bf16x8* Bsv = (const bf16x8*)Bs[cb];
    bf16x8 af[4], bfr[2];
#pragma unroll
    for (int i = 0; i < 4; i++) af[i]  = Asv[(wm + i * 16 + fr) * 4 + sw];
#pragma unroll
    for (int i = 0; i < 2; i++) bfr[i] = Bsv[(wn + i * 16 + fr) * 4 + sw];
#pragma unroll
    for (int mi = 0; mi < 4; mi++)
#pragma unroll
      for (int ni = 0; ni < 2; ni++)
        acc[mi][ni] = __builtin_amdgcn_mfma_f32_16x16x32_bf16(
            af[mi], bfr[ni], acc[mi][ni], 0, 0, 0);
    cb = (cb == 2) ? 0 : cb + 1;

    // fold at end of each source: bias + relu -> fp32 out_acc
    if (NSRC > 1) {
      if (++c_cnt == kc) {
        c_cnt = 0;
#pragma unroll
        for (int ni = 0; ni < 2; ni++) {
          const float bb = bias_v[0][ni + 0 * 2 + c_src * 2 - c_src * 2] // keep simple
                           ;
          (void)bb;
        }
#pragma unroll
        for (int mi = 0; mi < 4; mi++)
#pragma unroll
          for (int ni = 0; ni < 2; ni++)
#pragma unroll
            for (int j = 0; j < 4; j++) {
              float v = acc[mi][ni][j] + bias_v[c_src][ni];
              if (RELU) v = fmaxf(v, 0.0f);
              out_acc[mi][ni][j] += v;
              acc[mi][ni][j] = 0.0f;
            }
        ++c_src;
      }
    }
  }

  // store: C/D layout col = lane&15, row = (lane>>4)*4 + reg (verified R3)
#pragma unroll
  for (int ni = 0; ni < 2; ni++) {
    const int c = bn + wn + ni * 16 + fr;
    if (NGUARD && c >= N_real) continue;
#pragma unroll
    for (int mi = 0; mi < 4; mi++) {
      const int r0 = bm + wm + mi * 16 + kg * 4;
#pragma unroll
      for (int j = 0; j < 4; j++) {
        const size_t idx2 = (size_t)(r0 + j) * ldc + c;
        float v;
        if (NSRC == 1) {
          v = acc[mi][ni][j] + bias_v[0][ni];
          if (RELU) v = fmaxf(v, 0.0f);
        } else {
          v = out_acc[mi][ni][j];
        }
        if (of32) Cf[idx2] = v;
        else      C[idx2]  = (__hip_bfloat16)v;
      }
    }
  }
}

extern "C" void kernel_launch(void* const* d_in, const int* in_sizes, int n_in,
                              void* d_out, int out_size, void* d_ws, size_t ws_size,
                              hipStream_t stream) {
  (void)out_size; (void)ws_size;
  const int Bm = 8192, DIN = 2048, H = 1024, Cn = 1000;
  const size_t HH = (size_t)H * H;

  // ---- size-signature input resolver (verified R3) ----
  struct PO { const void* p; size_t off; };
  PO x{d_in[0], 0}, Wf{d_in[0], 0}, mf{d_in[0], 0}, Wo{d_in[0], 0}, mo{d_in[0], 0};
  PO bf{d_in[0], 0}, bo{d_in[0], 0};
  PO mW[4], mM[4], mB[4], sW[6], sM[6], sB[6];
  for (int i = 0; i < 4; i++) { mW[i] = {d_in[0], 0}; mM[i] = mW[i]; mB[i] = mW[i]; }
  for (int i = 0; i < 6; i++) { sW[i] = {d_in[0], 0}; sM[i] = sW[i]; sB[i] = sW[i]; }

  {
    int c2M = 0, c1M = 0, c1k = 0, cWoMo = 0, c4 = 0, c6 = 0;
    for (int i = 0; i < n_in; i++) {
      const int s = in_sizes[i];
      const void* p = d_in[i];
      switch (s) {
        case 16777216: x = {p, 0}; break;
        case 2097152:  if (c2M++ == 0) Wf = {p, 0}; else mf = {p, 0}; break;
        case 1048576: {
          int j = c1M++;
          if (j < 4)       mW[j]      = {p, 0};
          else if (j < 8)  mM[j - 4]  = {p, 0};
          else if (j < 14) sW[j - 8]  = {p, 0};
          else if (j < 20) sM[j - 14] = {p, 0};
          break;
        }
        case 1024: {
          int j = c1k++;
          if (j == 0)      bf        = {p, 0};
          else if (j < 5)  mB[j - 1] = {p, 0};
          else if (j < 11) sB[j - 5] = {p, 0};
          break;
        }
        case 1024000: if (cWoMo++ == 0) Wo = {p, 0}; else mo = {p, 0}; break;
        case 1000: bo = {p, 0}; break;
        case 4194304:
          for (int t = 0; t < 4; t++) {
            if (c4 == 0) mW[t] = {p, t * HH}; else mM[t] = {p, t * HH};
          }
          c4++; break;
        case 6291456:
          for (int t = 0; t < 6; t++) {
            if (c6 == 0) sW[t] = {p, t * HH}; else sM[t] = {p, t * HH};
          }
          c6++; break;
        case 4096:
          for (int t = 0; t < 4; t++) mB[t] = {p, (size_t)t * H};
          break;
        case 6144:
          for (int t = 0; t < 6; t++) sB[t] = {p, (size_t)t * H};
          break;
        default: break;
      }
    }
  }

  // ---- workspace layout (ushort units) ----
  ushort_t* wsp = (ushort_t*)d_ws;
  size_t off = 0;
  int* flags = (int*)wsp; off += 32;
  ushort_t* xc = wsp + off; off += (size_t)Bm * DIN;
  __hip_bfloat16* r[5];
  for (int i = 0; i < 5; i++) { r[i] = (__hip_bfloat16*)(wsp + off); off += (size_t)Bm * H; }
  ushort_t* wWf = wsp + off; off += (size_t)H * DIN;
  ushort_t* wMain[4];
  for (int i = 0; i < 4; i++) { wMain[i] = wsp + off; off += HH; }
  ushort_t* wSkip[6];
  for (int k = 0; k < 6; k++) { wSkip[k] = wsp + off; off += HH; }
  ushort_t* wWo = wsp + off; off += (size_t)1024 * 1024;  // zero-padded to 1024 rows
  ushort_t* cbf_ = wsp + off; off += 1024;
  ushort_t* cmB[4];
  for (int i = 0; i < 4; i++) { cmB[i] = wsp + off; off += 1024; }
  ushort_t* csB[6];
  for (int k = 0; k < 6; k++) { csB[k] = wsp + off; off += 1024; }
  ushort_t* cbo = wsp + off; off += 1024;                 // tail 1000..1023 zeroed

  // ---- launches ----
  detect_kernel<<<1, 256, 0, stream>>>((const ushort_t*)x.p, (const ushort_t*)mf.p, flags);

  PrepAll p;
  p.e[0]  = { Wf.p, Wf.off, mf.p, mf.off, wWf, H * DIN, H * DIN };
  for (int i = 0; i < 4; i++)
    p.e[1 + i] = { mW[i].p, mW[i].off, mM[i].p, mM[i].off, wMain[i], (int)HH, (int)HH };
  for (int k = 0; k < 6; k++)
    p.e[5 + k] = { sW[k].p, sW[k].off, sM[k].p, sM[k].off, wSkip[k], (int)HH, (int)HH };
  p.e[11] = { Wo.p, Wo.off, mo.p, mo.off, wWo, 1024 * 1024, Cn * H };
  p.e[12] = { bf.p, bf.off, nullptr, 0, cbf_, H, H };
  for (int i = 0; i < 4; i++)
    p.e[13 + i] = { mB[i].p, mB[i].off, nullptr, 0, cmB[i], H, H };
  for (int k = 0; k < 6; k++)
    p.e[17 + k] = { sB[k].p, sB[k].off, nullptr, 0, csB[k], H, H };
  p.e[23] = { bo.p, bo.off, nullptr, 0, cbo, 1024, Cn };
  p.e[24] = { x.p, x.off, nullptr, 0, xc, Bm * DIN, Bm * DIN };
  prep_weights<<<dim3(256, 25), dim3(256), 0, stream>>>(p, flags);

  const dim3 g(8, 64), b(512);

  GemmArgs a0; a0.s[0] = { xc, wWf, cbf_ };
  gemm_multi<1, true, false><<<g, b, 0, stream>>>(a0, r[0], nullptr, DIN, H, H);

  GemmArgs a1; a1.s[0] = { (ushort_t*)r[0], wMain[0], cmB[0] };
  gemm_multi<1, true, false><<<g, b, 0, stream>>>(a1, r[1], nullptr, H, H, H);

  GemmArgs a2;
  a2.s[0] = { (ushort_t*)r[1], wMain[1], cmB[1] };
  a2.s[1] = { (ushort_t*)r[0], wSkip[0], csB[0] };
  gemm_multi<2, true, false><<<g, b, 0, stream>>>(a2, r[2], nullptr, H, H, H);

  GemmArgs a3;
  a3.s[0] = { (ushort_t*)r[2], wMain[2], cmB[2] };
  a3.s[1] = { (ushort_t*)r[0], wSkip[1], csB[1] };
  a3.s[2] = { (ushort_t*)r[1], wSkip[2], csB[2] };
  gemm_multi<3, true, false><<<g, b, 0, stream>>>(a3, r[3], nullptr, H, H, H);

  GemmArgs a4;
  a4.s[0] = { (ushort_t*)r[3], wMain[3], cmB[3] };
  a4.s[1] = { (ushort_t*)r[0], wSkip[3], csB[3] };
  a4.s[2] = { (ushort_t*)r[1], wSkip[4], csB[4] };
  a4.s[3] = { (ushort_t*)r[2], wSkip[5], csB[5] };
  gemm_multi<4, true, false><<<g, b, 0, stream>>>(a4, r[4], nullptr, H, H, H);

  GemmArgs ao; ao.s[0] = { (ushort_t*)r[4], wWo, cbo };
  gemm_multi<1, false, true><<<g, b, 0, stream>>>(ao, d_out, flags, H, Cn, Cn);
}